// Round 9
// baseline (8751.956 us; speedup 1.0000x reference)
//
#include <hip/hip_runtime.h>
#include <hip/hip_bf16.h>

#define BB 8
#define NN 2048
#define KK 20
#define BN (BB*NN)
#define MSPLIT 8   // partial lists per n (one per z-chunk of 256 m)
#define RSQ 0.99999500003749969f   // 1/sqrt(1+1e-5)

// ---------------- workspace layout (float-slot units), 44.3 MiB total ----------------
constexpr size_t OFF_X1  = 0;                          // BN*64
constexpr size_t OFF_X2  = OFF_X1  + (size_t)BN*64;    // BN*64
constexpr size_t OFF_X3  = OFF_X2  + (size_t)BN*64;    // BN*128
constexpr size_t OFF_X4  = OFF_X3  + (size_t)BN*128;   // BN*256 (pv/pi alias here during knn)
constexpr size_t OFF_XX  = OFF_X4  + (size_t)BN*256;   // BN
constexpr size_t OFF_SC  = OFF_XX  + BN;               // scratch: q,bs (BN*128 of BN*160)
constexpr size_t OFF_ID  = OFF_SC  + (size_t)BN*160;   // int BN*20
constexpr size_t OFF_W5T = OFF_ID  + (size_t)BN*20;    // 512*512, [c][o]
constexpr size_t OFF_MX  = OFF_W5T + 512*512;          // uint B*512
constexpr size_t OFF_MN  = OFF_MX  + BB*512;
constexpr size_t WS_END  = OFF_MN  + BB*512;           // 11,624,448 floats

__device__ inline unsigned encf(float f){ unsigned u=__float_as_uint(f); return (u&0x80000000u)? ~u : (u|0x80000000u); }
__device__ inline float decf(unsigned e){ unsigned u=(e&0x80000000u)? (e&0x7fffffffu) : ~e; return __uint_as_float(u); }
__device__ inline float lrelu(float h){ return h>=0.f ? h : 0.2f*h; }

__device__ inline void ins20(float (&val)[KK], int (&ind)[KK], float cv, int ci){
  if (cv > val[KK-1]){
    #pragma unroll
    for(int j=0;j<KK;j++){
      if (cv > val[j]){ float tv=val[j]; int ti=ind[j]; val[j]=cv; ind[j]=ci; cv=tv; ci=ti; }
    }
  }
}

// ---------------- init ----------------
__global__ void transposeW5_k(const float* s, float* d){
  int i = blockIdx.x*256 + threadIdx.x;   // 262144
  int o = i>>9, c = i&511;
  d[c*512+o] = s[i];
}
__global__ void init_enc_k(unsigned* mx, unsigned* mn){
  int i = blockIdx.x*256 + threadIdx.x;   // 4096
  mx[i] = 0x007FFFFFu;   // enc(-inf)
  mn[i] = 0xFF800000u;   // enc(+inf)
}

// ---------------- KNN ----------------
template<int C>
__launch_bounds__(256) __global__ void sqnorm_k(const float* X, float* xx){
  int i = blockIdx.x*256 + threadIdx.x;   // BN
  const float* r = X + (size_t)i*C;
  float s = 0.f;
  #pragma unroll
  for(int c=0;c<C;c++) s = fmaf(r[c], r[c], s);
  xx[i] = s;
}

// per-n kernel kept only for C=3
template<int C, int MC>
__launch_bounds__(256) __global__ void knn_part2_k(const float* __restrict__ X, const float* __restrict__ xx,
                                                   float* __restrict__ pval, unsigned short* __restrict__ pidx){
  __shared__ float sm[MC*C];
  __shared__ float sxx[MC];
  const int b   = blockIdx.y;
  const int tid = threadIdx.x;
  const int n   = blockIdx.x*256 + tid;
  const float* Xb = X + (size_t)b*NN*C;
  float xn[C];
  #pragma unroll
  for(int c=0;c<C;c++) xn[c] = Xb[(size_t)n*C + c];
  const float xxn = xx[b*NN+n];
  const float* xxb = xx + b*NN;
  float val[KK]; int ind[KK];
  #pragma unroll
  for(int j=0;j<KK;j++){ val[j]=-INFINITY; ind[j]=0; }

  const int m0 = blockIdx.z*(NN/MSPLIT);
  for(int ms=m0; ms<m0+NN/MSPLIT; ms+=MC){
    __syncthreads();
    for(int i=tid; i<MC*C; i+=256) sm[i] = Xb[(size_t)ms*C + i];
    for(int i=tid; i<MC; i+=256) sxx[i] = xxb[ms+i];
    __syncthreads();
    for(int mg=0; mg<MC; mg+=4){
      float a0=0.f, a1=0.f, a2=0.f, a3=0.f;
      #pragma unroll
      for(int c=0;c<C;c++){
        float xc = xn[c];
        a0=fmaf(xc, sm[(size_t)(mg+0)*C+c], a0);
        a1=fmaf(xc, sm[(size_t)(mg+1)*C+c], a1);
        a2=fmaf(xc, sm[(size_t)(mg+2)*C+c], a2);
        a3=fmaf(xc, sm[(size_t)(mg+3)*C+c], a3);
      }
      float d0 = (2.f*a0 - xxn) - sxx[mg+0];
      float d1 = (2.f*a1 - xxn) - sxx[mg+1];
      float d2 = (2.f*a2 - xxn) - sxx[mg+2];
      float d3 = (2.f*a3 - xxn) - sxx[mg+3];
      float mx4 = fmaxf(fmaxf(d0,d1), fmaxf(d2,d3));
      if (mx4 > val[KK-1]){
        ins20(val, ind, d0, ms+mg+0);
        ins20(val, ind, d1, ms+mg+1);
        ins20(val, ind, d2, ms+mg+2);
        ins20(val, ind, d3, ms+mg+3);
      }
    }
  }
  float*          pv = pval + (((size_t)(b*NN+n))*MSPLIT + blockIdx.z)*KK;
  unsigned short* pi = pidx + (((size_t)(b*NN+n))*MSPLIT + blockIdx.z)*KK;
  #pragma unroll
  for(int j=0;j<KK;j++){ pv[j]=val[j]; pi[j]=(unsigned short)ind[j]; }
}

// GEMM-tiled KNN v3: block = 128n x 64m subtile, thread = 8n x 4m (32 acc regs).
// z in [0,8): chunk of 256 m = 4 subtiles of 64 m. Selection: threads 0..127 scan
// one full 64-m row each -> exactly one partial list per (n, z), 8 lists total.
// Register demand ~97 < 128 budget -> no spill (R8 lesson: spills were the wall).
// Accumulation per (n,m): single fmaf chain, c ascending -> bit-identical.
template<int C>
__launch_bounds__(256) __global__ void knn_gemm_k(const float* __restrict__ X, const float* __restrict__ xx,
                                                  float* __restrict__ pval, unsigned short* __restrict__ pidx){
  constexpr int AST = 132;   // a_sh [c][n] row stride
  constexpr int BST = 68;    // b_sh [c][m] row stride
  constexpr int DST = 65;    // d_sh [n][m] row stride (selection reads 2-way = free)
  __shared__ __align__(16) float a_sh[16*AST];
  __shared__ __align__(16) float b_sh[16*BST];
  __shared__ float d_sh[128*DST];
  __shared__ float sxx[64];

  const int tid = threadIdx.x;
  const int b   = blockIdx.y;
  const int ntile = blockIdx.x*128;
  const int z   = blockIdx.z;
  const int tn  = tid & 15;        // n-group (8 rows each)
  const int tm  = tid >> 4;        // m-group (4 cols each)

  const float* Xb  = X  + (size_t)b*NN*C;
  const float* xxb = xx + (size_t)b*NN;
  const float xxn_sel = xxb[ntile + (tid & 127)];

  float val[KK]; int ind[KK];
  #pragma unroll
  for(int j=0;j<KK;j++){ val[j]=-INFINITY; ind[j]=0; }

  for(int mt=0; mt<4; ++mt){
    const int mtile = z*256 + mt*64;
    float acc[8][4];
    #pragma unroll
    for(int i=0;i<8;i++){
      #pragma unroll
      for(int j=0;j<4;j++) acc[i][j]=0.f;
    }
    for(int cc=0; cc<C; cc+=16){
      __syncthreads();                 // prev frag reads / prev selection done
      #pragma unroll
      for(int s=0;s<2;s++){            // A: 128 rows x 16 c
        int ii = tid + 256*s;
        int r = ii>>2, q = ii&3;
        float4 va = *(const float4*)&Xb[(size_t)(ntile + r)*C + cc + 4*q];
        a_sh[(4*q+0)*AST + r]=va.x; a_sh[(4*q+1)*AST + r]=va.y;
        a_sh[(4*q+2)*AST + r]=va.z; a_sh[(4*q+3)*AST + r]=va.w;
      }
      {                                // B: 64 rows x 16 c
        int r = tid>>2, q = tid&3;
        float4 vb = *(const float4*)&Xb[(size_t)(mtile + r)*C + cc + 4*q];
        b_sh[(4*q+0)*BST + r]=vb.x; b_sh[(4*q+1)*BST + r]=vb.y;
        b_sh[(4*q+2)*BST + r]=vb.z; b_sh[(4*q+3)*BST + r]=vb.w;
      }
      __syncthreads();
      #pragma unroll
      for(int c=0;c<16;c++){
        float4 A0 = *(const float4*)&a_sh[c*AST + tn*8];
        float4 A1 = *(const float4*)&a_sh[c*AST + tn*8 + 4];
        float4 Bv = *(const float4*)&b_sh[c*BST + tm*4];
        float ar[8] = {A0.x,A0.y,A0.z,A0.w,A1.x,A1.y,A1.z,A1.w};
        #pragma unroll
        for(int i=0;i<8;i++){
          acc[i][0] = fmaf(ar[i], Bv.x, acc[i][0]);
          acc[i][1] = fmaf(ar[i], Bv.y, acc[i][1]);
          acc[i][2] = fmaf(ar[i], Bv.z, acc[i][2]);
          acc[i][3] = fmaf(ar[i], Bv.w, acc[i][3]);
        }
      }
    }
    // write distances to d_sh (acc dies here), stage sxx
    #pragma unroll
    for(int i=0;i<8;i++){
      #pragma unroll
      for(int j=0;j<4;j++)
        d_sh[(size_t)(tn*8+i)*DST + tm*4 + j] = acc[i][j];
    }
    if(tid < 64) sxx[tid] = xxb[mtile + tid];
    __syncthreads();
    if(tid < 128){                     // selection: one full 64-m row per n
      #pragma unroll
      for(int j4=0;j4<16;j4++){
        int mj = 4*j4;
        float v0 = d_sh[(size_t)tid*DST + mj+0];
        float v1 = d_sh[(size_t)tid*DST + mj+1];
        float v2 = d_sh[(size_t)tid*DST + mj+2];
        float v3 = d_sh[(size_t)tid*DST + mj+3];
        float d0 = (2.f*v0 - xxn_sel) - sxx[mj+0];
        float d1 = (2.f*v1 - xxn_sel) - sxx[mj+1];
        float d2 = (2.f*v2 - xxn_sel) - sxx[mj+2];
        float d3 = (2.f*v3 - xxn_sel) - sxx[mj+3];
        float mx4 = fmaxf(fmaxf(d0,d1), fmaxf(d2,d3));
        if(mx4 > val[KK-1]){
          ins20(val,ind,d0, mtile+mj+0);
          ins20(val,ind,d1, mtile+mj+1);
          ins20(val,ind,d2, mtile+mj+2);
          ins20(val,ind,d3, mtile+mj+3);
        }
      }
    }
    __syncthreads();                   // d_sh reads done before next mt's writes
  }
  if(tid < 128){
    const int n = ntile + tid;
    float*          pv = pval + (((size_t)(b*NN + n))*8 + z)*KK;
    unsigned short* pi = pidx + (((size_t)(b*NN + n))*8 + z)*KK;
    #pragma unroll
    for(int j=0;j<KK;j++){ pv[j]=val[j]; pi[j]=(unsigned short)ind[j]; }
  }
}

__launch_bounds__(256) __global__ void knn_merge_k(const float* pval, const unsigned short* pidx, int* idx){
  int i = blockIdx.x*256 + threadIdx.x;   // BN
  const float* pv = pval + (size_t)i*MSPLIT*KK;
  const unsigned short* pi = pidx + (size_t)i*MSPLIT*KK;
  int* out = idx + (size_t)i*KK;
  float cv[MSPLIT]; int ci[MSPLIT]; int hp[MSPLIT];
  #pragma unroll
  for(int l=0;l<MSPLIT;l++){ cv[l]=pv[(size_t)l*KK]; ci[l]=pi[(size_t)l*KK]; hp[l]=1; }
  for(int j=0;j<KK;j++){
    float bv=-INFINITY; int bi=0x7fffffff; int bl=0;
    #pragma unroll
    for(int l=0;l<MSPLIT;l++){
      if (cv[l]>bv || (cv[l]==bv && ci[l]<bi)){ bv=cv[l]; bi=ci[l]; bl=l; }
    }
    out[j]=bi;
    if(hp[bl]<KK){ cv[bl]=pv[(size_t)bl*KK+hp[bl]]; ci[bl]=pi[(size_t)bl*KK+hp[bl]]; hp[bl]++; }
    else cv[bl]=-INFINITY;
  }
}

// ---------------- per-64-column qp + gather ----------------
template<int CIN>
__launch_bounds__(256) __global__ void qp64_k(const float* X, const float* W, int cb,
                                              float* q, float* bs){
  const int t   = blockIdx.x*256 + threadIdx.x;  // BN*8
  const int row = t >> 3;
  const int c0  = (t & 7) * 8;
  float xn[CIN];
  if constexpr (CIN % 4 == 0){
    #pragma unroll
    for(int c=0;c<CIN;c+=4){ float4 v = *(const float4*)(X + (size_t)row*CIN + c);
      xn[c]=v.x; xn[c+1]=v.y; xn[c+2]=v.z; xn[c+3]=v.w; }
  } else {
    #pragma unroll
    for(int c=0;c<CIN;c++) xn[c] = X[(size_t)row*CIN + c];
  }
  for(int oi=c0; oi<c0+8; oi++){
    const float* w = W + (size_t)(cb+oi)*2*CIN;
    float aq=0.f, ap=0.f;
    #pragma unroll
    for(int c=0;c<CIN;c++){ aq = fmaf(xn[c], w[c], aq); ap = fmaf(xn[c], w[CIN+c], ap); }
    q [(size_t)row*64 + oi] = aq;
    bs[(size_t)row*64 + oi] = ap - aq;
  }
}

template<int CFULL>
__launch_bounds__(256) __global__ void gather64_k(const float* q, const float* bs, const int* idx,
    const float* g, const float* bb, int cb, float* out){
  const int t  = blockIdx.x*256 + threadIdx.x;   // BN*64
  const int o  = t & 63;
  const int bn = t >> 6;
  const int b  = bn >> 11;
  const int* id = idx + (size_t)bn*KK;
  float base = bs[t];
  float mx = -INFINITY, mn = INFINITY;
  #pragma unroll
  for(int k=0;k<KK;k++){
    int ik = id[k];
    float v = q[((size_t)((b<<11) + ik))*64 + o];
    mx = fmaxf(mx, v); mn = fminf(mn, v);
  }
  float a  = g[cb+o] * RSQ;
  float bo = bb[cb+o];
  float h  = lrelu((a >= 0.f ? a*(mx+base) : a*(mn+base)) + bo);
  out[(size_t)bn*CFULL + cb + o] = h;
}

// ---------------- head: cat*W5^T with fused max/min over n ----------------
__launch_bounds__(256) __global__ void w5max_k(const float* x1,const float* x2,const float* x3,
    const float* x4, const float* W5T, unsigned* mxe, unsigned* mne){
  __shared__ float cat[16*512];
  __shared__ float redm[512], redn[512];
  const int blk = blockIdx.x;             // 1024 = B * (N/16)
  const int b  = blk >> 7;
  const int r0 = (blk & 127)*16;
  const int t  = threadIdx.x;
  const size_t bn0 = (size_t)b*NN + r0;
  for(int i=t; i<16*512; i+=256){
    int r = i>>9, c = i&511;
    size_t row = bn0 + r;
    float v;
    if(c<64)       v = x1[row*64  + c];
    else if(c<128) v = x2[row*64  + (c-64)];
    else if(c<256) v = x3[row*128 + (c-128)];
    else           v = x4[row*256 + (c-256)];
    cat[i] = v;
  }
  __syncthreads();
  const int half = t>>7, tq = t&127;
  const int rbase = half*8;
  float acc[4][8];
  #pragma unroll
  for(int j=0;j<4;j++){
    #pragma unroll
    for(int r=0;r<8;r++) acc[j][r]=0.f;
  }
  for(int c=0;c<512;c+=4){
    float w[4][4];
    #pragma unroll
    for(int cc=0;cc<4;cc++){
      #pragma unroll
      for(int j=0;j<4;j++) w[cc][j] = W5T[(size_t)(c+cc)*512 + tq + 128*j];
    }
    #pragma unroll
    for(int r=0;r<8;r++){
      float4 cv = *(const float4*)&cat[(rbase+r)*512 + c];
      #pragma unroll
      for(int j=0;j<4;j++)
        acc[j][r] = fmaf(cv.x, w[0][j], fmaf(cv.y, w[1][j], fmaf(cv.z, w[2][j], fmaf(cv.w, w[3][j], acc[j][r]))));
    }
  }
  float lmx[4], lmn[4];
  #pragma unroll
  for(int j=0;j<4;j++){
    float M=-INFINITY, m=INFINITY;
    #pragma unroll
    for(int r=0;r<8;r++){ M=fmaxf(M,acc[j][r]); m=fminf(m,acc[j][r]); }
    lmx[j]=M; lmn[j]=m;
  }
  if(half==0){
    #pragma unroll
    for(int j=0;j<4;j++){ redm[tq+128*j]=lmx[j]; redn[tq+128*j]=lmn[j]; }
  }
  __syncthreads();
  if(half==1){
    #pragma unroll
    for(int j=0;j<4;j++){
      int o = tq + 128*j;
      float M = fmaxf(lmx[j], redm[o]);
      float m = fminf(lmn[j], redn[o]);
      atomicMax(&mxe[b*512+o], encf(M));
      atomicMin(&mne[b*512+o], encf(m));
    }
  }
}

__launch_bounds__(256) __global__ void final_k(const unsigned* mxe, const unsigned* mne,
    const float* g5, const float* b5, const float* Wemb, float* out){
  const int b = blockIdx.x, t = threadIdx.x;
  __shared__ float h[512];
  for(int o=t; o<512; o+=256){
    float mx = decf(mxe[b*512+o]);
    float mn = decf(mne[b*512+o]);
    float a  = g5[o] * RSQ;
    float bo = b5[o];
    float hv = lrelu((a >= 0.f ? a*mx : a*mn) + bo);
    h[o] = hv;
    out[b*512+o] = hv;                       // feat (B,1,512)
  }
  __syncthreads();
  const float* wr = Wemb + (size_t)t*512;
  float s = 0.f;
  for(int o=0;o<512;o+=4){
    float4 w4 = *(const float4*)(wr+o);
    s = fmaf(h[o],w4.x, fmaf(h[o+1],w4.y, fmaf(h[o+2],w4.z, fmaf(h[o+3],w4.w, s))));
  }
  out[4096 + b*256 + t] = s;                 // embedding (B,256)
}

// ---------------- launch ----------------
extern "C" void kernel_launch(void* const* d_in, const int* in_sizes, int n_in,
                              void* d_out, int out_size, void* d_ws, size_t ws_size,
                              hipStream_t stream) {
  if (ws_size < WS_END * sizeof(float)) return;   // diagnostic guard

  const float* x0   = (const float*)d_in[0];
  const float* W1   = (const float*)d_in[1];
  const float* g1   = (const float*)d_in[2];
  const float* b1   = (const float*)d_in[3];
  const float* W2   = (const float*)d_in[4];
  const float* g2   = (const float*)d_in[5];
  const float* b2   = (const float*)d_in[6];
  const float* W3   = (const float*)d_in[7];
  const float* g3   = (const float*)d_in[8];
  const float* b3   = (const float*)d_in[9];
  const float* W4   = (const float*)d_in[10];
  const float* g4   = (const float*)d_in[11];
  const float* b4   = (const float*)d_in[12];
  const float* W5   = (const float*)d_in[13];
  const float* g5   = (const float*)d_in[14];
  const float* b5   = (const float*)d_in[15];
  const float* Wemb = (const float*)d_in[16];

  float* ws = (float*)d_ws;
  float* x1 = ws + OFF_X1;  float* x2 = ws + OFF_X2;
  float* x3 = ws + OFF_X3;  float* x4 = ws + OFF_X4;
  float* xx = ws + OFF_XX;
  // pv/pi alias into x4 (dead during all knn phases)
  float*          pv = ws + OFF_X4;
  unsigned short* pi = (unsigned short*)(ws + OFF_X4 + (size_t)BN*MSPLIT*KK);
  float* q  = ws + OFF_SC;
  float* bs = ws + OFF_SC + (size_t)BN*64;
  int*   id = (int*)(ws + OFF_ID);
  float* W5Tf = ws + OFF_W5T;
  unsigned* mxe = (unsigned*)(ws + OFF_MX);
  unsigned* mne = (unsigned*)(ws + OFF_MN);
  float* out = (float*)d_out;

  transposeW5_k<<<262144/256,256,0,stream>>>(W5, W5Tf);
  init_enc_k<<<BB*512/256,256,0,stream>>>(mxe, mne);

  dim3 ggrid(NN/128, BB, 8);

  // layer 1 (3 -> 64)
  sqnorm_k<3><<<BN/256,256,0,stream>>>(x0, xx);
  knn_part2_k<3,256><<<dim3(NN/256,BB,MSPLIT),256,0,stream>>>(x0, xx, pv, pi);
  knn_merge_k<<<BN/256,256,0,stream>>>(pv, pi, id);
  qp64_k<3><<<BN*8/256,256,0,stream>>>(x0, W1, 0, q, bs);
  gather64_k<64><<<BN*64/256,256,0,stream>>>(q, bs, id, g1, b1, 0, x1);

  // layer 2 (64 -> 64)
  sqnorm_k<64><<<BN/256,256,0,stream>>>(x1, xx);
  knn_gemm_k<64><<<ggrid,256,0,stream>>>(x1, xx, pv, pi);
  knn_merge_k<<<BN/256,256,0,stream>>>(pv, pi, id);
  qp64_k<64><<<BN*8/256,256,0,stream>>>(x1, W2, 0, q, bs);
  gather64_k<64><<<BN*64/256,256,0,stream>>>(q, bs, id, g2, b2, 0, x2);

  // layer 3 (64 -> 128)
  sqnorm_k<64><<<BN/256,256,0,stream>>>(x2, xx);
  knn_gemm_k<64><<<ggrid,256,0,stream>>>(x2, xx, pv, pi);
  knn_merge_k<<<BN/256,256,0,stream>>>(pv, pi, id);
  for(int cb=0; cb<128; cb+=64){
    qp64_k<64><<<BN*8/256,256,0,stream>>>(x2, W3, cb, q, bs);
    gather64_k<128><<<BN*64/256,256,0,stream>>>(q, bs, id, g3, b3, cb, x3);
  }

  // layer 4 (128 -> 256)
  sqnorm_k<128><<<BN/256,256,0,stream>>>(x3, xx);
  knn_gemm_k<128><<<ggrid,256,0,stream>>>(x3, xx, pv, pi);
  knn_merge_k<<<BN/256,256,0,stream>>>(pv, pi, id);
  for(int cb=0; cb<256; cb+=64){
    qp64_k<128><<<BN*8/256,256,0,stream>>>(x3, W4, cb, q, bs);
    gather64_k<256><<<BN*64/256,256,0,stream>>>(q, bs, id, g4, b4, cb, x4);
  }

  // head
  w5max_k<<<BB*(NN/16),256,0,stream>>>(x1, x2, x3, x4, W5Tf, mxe, mne);
  final_k<<<BB,256,0,stream>>>(mxe, mne, g5, b5, Wemb, out);
}

// Round 10
// 2199.450 us; speedup vs baseline: 3.9792x; 3.9792x over previous
//
#include <hip/hip_runtime.h>
#include <hip/hip_bf16.h>

#define BB 8
#define NN 2048
#define KK 20
#define BN (BB*NN)
#define RSQ 0.99999500003749969f   // 1/sqrt(1+1e-5)

// ---------------- workspace layout (float-slot units), 44.3 MiB total ----------------
constexpr size_t OFF_XX  = 0;                          // BN
constexpr size_t OFF_X1  = OFF_XX  + BN;               // BN*64
constexpr size_t OFF_X2  = OFF_X1  + (size_t)BN*64;    // BN*64
constexpr size_t OFF_X3  = OFF_X2  + (size_t)BN*64;    // BN*128
constexpr size_t OFF_X4  = OFF_X3  + (size_t)BN*128;   // BN*256
constexpr size_t OFF_SC  = OFF_X4  + (size_t)BN*256;   // BN*160 (q,bs post-knn)
constexpr size_t OFF_ID  = OFF_SC  + (size_t)BN*160;   // int BN*20
constexpr size_t OFF_W5T = OFF_ID  + (size_t)BN*20;    // 512*512
constexpr size_t OFF_MX  = OFF_W5T + 512*512;
constexpr size_t OFF_MN  = OFF_MX  + BB*512;
constexpr size_t WS_END  = OFF_MN  + BB*512;
// dist buffers (time-shared):
//  dual-batch (4096x2048 = 8.39M floats) at OFF_X3: x3+x4+SC span = BN*544 = 8.91M ✓
//    (x3,x4 dead during L1/L2/L3 knn; SC dead during knn; L3 input x2 untouched)
//  single-batch (2048x2048 = 4.19M floats) at OFF_X4 for L4 (x3 live, x4 dead) ✓
static_assert(OFF_ID - OFF_X3 >= (size_t)4096*2048, "dual dist fits");

__device__ inline unsigned encf(float f){ unsigned u=__float_as_uint(f); return (u&0x80000000u)? ~u : (u|0x80000000u); }
__device__ inline float decf(unsigned e){ unsigned u=(e&0x80000000u)? (e&0x7fffffffu) : ~e; return __uint_as_float(u); }
__device__ inline float lrelu(float h){ return h>=0.f ? h : 0.2f*h; }

// ---------------- init ----------------
__global__ void transposeW5_k(const float* s, float* d){
  int i = blockIdx.x*256 + threadIdx.x;   // 262144
  int o = i>>9, c = i&511;
  d[c*512+o] = s[i];
}
__global__ void init_enc_k(unsigned* mx, unsigned* mn){
  int i = blockIdx.x*256 + threadIdx.x;   // 4096
  mx[i] = 0x007FFFFFu;
  mn[i] = 0xFF800000u;
}

// ---------------- KNN ----------------
template<int C>
__launch_bounds__(256) __global__ void sqnorm_k(const float* X, float* xx){
  int i = blockIdx.x*256 + threadIdx.x;   // BN
  const float* r = X + (size_t)i*C;
  float s = 0.f;
  #pragma unroll
  for(int c=0;c<C;c++) s = fmaf(r[c], r[c], s);
  xx[i] = s;
}

// C=3 distance rows: block = one row (n), thread computes 8 m.
__launch_bounds__(256) __global__ void dist3_k(const float* __restrict__ X, const float* __restrict__ xx,
                                               float* __restrict__ dist, int b0){
  const int row = blockIdx.x;            // 0..NB*2048-1
  const int b   = b0 + (row >> 11);
  const int n   = row & 2047;
  const int m0  = threadIdx.x * 8;
  const float* Xb = X + (size_t)b*NN*3;
  float x0 = Xb[n*3], x1 = Xb[n*3+1], x2 = Xb[n*3+2];
  float xxn = xx[b*NN + n];
  const float* xxm = xx + b*NN + m0;
  float* dr = dist + (size_t)row*NN + m0;
  #pragma unroll
  for(int j=0;j<8;j++){
    int m = m0 + j;
    float s = 0.f;
    s = fmaf(x0, Xb[m*3+0], s);
    s = fmaf(x1, Xb[m*3+1], s);
    s = fmaf(x2, Xb[m*3+2], s);
    dr[j] = (2.f*s - xxn) - xxm[j];
  }
}

#define FMA_ROW(I) \
  acc[I][0]=fmaf(a,b0v,acc[I][0]); acc[I][1]=fmaf(a,b1v,acc[I][1]); \
  acc[I][2]=fmaf(a,b2v,acc[I][2]); acc[I][3]=fmaf(a,b3v,acc[I][3]); \
  acc[I][4]=fmaf(a,b4v,acc[I][4]); acc[I][5]=fmaf(a,b5v,acc[I][5]); \
  acc[I][6]=fmaf(a,b6v,acc[I][6]); acc[I][7]=fmaf(a,b7v,acc[I][7]);

// Pure GEMM distance kernel: 128n x 128m tile, 8x8 micro-tile, writes negd to global.
// A/B LDS layout staggered: col r at p(r)=r+4*(r>>3) -> frag reads 2-way (free).
// No selection state -> ~95 VGPR, no spill (R8/R9 lesson).
template<int C>
__launch_bounds__(256) __global__ void gemm_dist_k(const float* __restrict__ X, const float* __restrict__ xx,
                                                   float* __restrict__ dist, int b0){
  constexpr int AST = 188;
  __shared__ __align__(16) float a_sh[16*AST];
  __shared__ __align__(16) float b_sh[16*AST];
  __shared__ float sxn[128], sxm[128];
  const int tid = threadIdx.x;
  const int b   = b0 + blockIdx.z;
  const int mtile = blockIdx.x*128;
  const int ntile = blockIdx.y*128;
  const int tn = tid & 15, tm = tid >> 4;
  const float* Xb  = X  + (size_t)b*NN*C;
  const float* xxb = xx + (size_t)b*NN;
  if(tid < 128) sxn[tid] = xxb[ntile + tid];
  else          sxm[tid-128] = xxb[mtile + tid-128];
  float acc[8][8];
  #pragma unroll
  for(int i=0;i<8;i++){
    #pragma unroll
    for(int j=0;j<8;j++) acc[i][j]=0.f;
  }
  for(int cc=0; cc<C; cc+=16){
    __syncthreads();
    #pragma unroll
    for(int s=0;s<2;s++){
      int ii = tid + 256*s; int r = ii>>2, q = ii&3;
      int pr = r + 4*(r>>3);
      float4 va = *(const float4*)&Xb[(size_t)(ntile + r)*C + cc + 4*q];
      a_sh[(4*q+0)*AST + pr]=va.x; a_sh[(4*q+1)*AST + pr]=va.y;
      a_sh[(4*q+2)*AST + pr]=va.z; a_sh[(4*q+3)*AST + pr]=va.w;
      float4 vb = *(const float4*)&Xb[(size_t)(mtile + r)*C + cc + 4*q];
      b_sh[(4*q+0)*AST + pr]=vb.x; b_sh[(4*q+1)*AST + pr]=vb.y;
      b_sh[(4*q+2)*AST + pr]=vb.z; b_sh[(4*q+3)*AST + pr]=vb.w;
    }
    __syncthreads();
    #pragma unroll
    for(int c=0;c<16;c++){
      float4 A0 = *(const float4*)&a_sh[c*AST + 12*tn];
      float4 A1 = *(const float4*)&a_sh[c*AST + 12*tn + 4];
      float4 B0 = *(const float4*)&b_sh[c*AST + 12*tm];
      float4 B1 = *(const float4*)&b_sh[c*AST + 12*tm + 4];
      float b0v=B0.x,b1v=B0.y,b2v=B0.z,b3v=B0.w,b4v=B1.x,b5v=B1.y,b6v=B1.z,b7v=B1.w;
      float a;
      a=A0.x; FMA_ROW(0)
      a=A0.y; FMA_ROW(1)
      a=A0.z; FMA_ROW(2)
      a=A0.w; FMA_ROW(3)
      a=A1.x; FMA_ROW(4)
      a=A1.y; FMA_ROW(5)
      a=A1.z; FMA_ROW(6)
      a=A1.w; FMA_ROW(7)
    }
  }
  float xnr[8], xmr[8];
  #pragma unroll
  for(int i=0;i<8;i++){ xnr[i]=sxn[tn*8+i]; xmr[i]=sxm[tm*8+i]; }
  const size_t rowb = (size_t)blockIdx.z*NN + ntile + tn*8;
  #pragma unroll
  for(int i=0;i<8;i++){
    float4 w0, w1;
    w0.x=(2.f*acc[i][0]-xnr[i])-xmr[0]; w0.y=(2.f*acc[i][1]-xnr[i])-xmr[1];
    w0.z=(2.f*acc[i][2]-xnr[i])-xmr[2]; w0.w=(2.f*acc[i][3]-xnr[i])-xmr[3];
    w1.x=(2.f*acc[i][4]-xnr[i])-xmr[4]; w1.y=(2.f*acc[i][5]-xnr[i])-xmr[5];
    w1.z=(2.f*acc[i][6]-xnr[i])-xmr[6]; w1.w=(2.f*acc[i][7]-xnr[i])-xmr[7];
    float* dp = dist + (rowb + i)*NN + mtile + tm*8;
    *(float4*)dp = w0;
    *(float4*)(dp+4) = w1;
  }
}

// Wave-cooperative top-20: one wave per n-row; sorted list in lanes 0..19.
// Wave-uniform control (ballot-driven) -> no divergence tax; insert ~12 instr.
__launch_bounds__(256) __global__ void sel_k(const float* __restrict__ dist, int* __restrict__ id,
                                             int b0, int nrows){
  const int w = (blockIdx.x*256 + threadIdx.x) >> 6;   // row within round
  const int lane = threadIdx.x & 63;
  if(w >= nrows) return;
  const float* dr = dist + (size_t)w*NN;
  float lv = -INFINITY; int li = 0;
  float theta = -INFINITY;
  for(int ms=0; ms<NN; ms+=64){
    float cand = dr[ms + lane];
    unsigned long long bal = __ballot(cand > theta);
    while(bal){
      int bpos = __ffsll((unsigned long long)bal) - 1;
      bal &= bal - 1;
      float cv = __shfl(cand, bpos);
      if(cv > theta){                      // theta may have risen; wave-uniform branch
        int ci = ms + bpos;
        unsigned long long mge = __ballot(lv >= cv);
        int pos = __popcll(mge);           // stable: equals stay ahead (lower idx first)
        float upv = __shfl_up(lv, 1);
        int   upi = __shfl_up(li, 1);
        bool shift = (lane > pos) && (lane < KK);
        lv = (lane == pos) ? cv : (shift ? upv : lv);
        li = (lane == pos) ? ci : (shift ? upi : li);
        theta = __shfl(lv, KK-1);
      }
    }
  }
  if(lane < KK) id[((size_t)b0*NN + w)*KK + lane] = li;
}

// ---------------- per-64-column qp + gather ----------------
template<int CIN>
__launch_bounds__(256) __global__ void qp64_k(const float* X, const float* W, int cb,
                                              float* q, float* bs){
  const int t   = blockIdx.x*256 + threadIdx.x;  // BN*8
  const int row = t >> 3;
  const int c0  = (t & 7) * 8;
  float xn[CIN];
  if constexpr (CIN % 4 == 0){
    #pragma unroll
    for(int c=0;c<CIN;c+=4){ float4 v = *(const float4*)(X + (size_t)row*CIN + c);
      xn[c]=v.x; xn[c+1]=v.y; xn[c+2]=v.z; xn[c+3]=v.w; }
  } else {
    #pragma unroll
    for(int c=0;c<CIN;c++) xn[c] = X[(size_t)row*CIN + c];
  }
  for(int oi=c0; oi<c0+8; oi++){
    const float* w = W + (size_t)(cb+oi)*2*CIN;
    float aq=0.f, ap=0.f;
    #pragma unroll
    for(int c=0;c<CIN;c++){ aq = fmaf(xn[c], w[c], aq); ap = fmaf(xn[c], w[CIN+c], ap); }
    q [(size_t)row*64 + oi] = aq;
    bs[(size_t)row*64 + oi] = ap - aq;
  }
}

template<int CFULL>
__launch_bounds__(256) __global__ void gather64_k(const float* q, const float* bs, const int* idx,
    const float* g, const float* bb, int cb, float* out){
  const int t  = blockIdx.x*256 + threadIdx.x;   // BN*64
  const int o  = t & 63;
  const int bn = t >> 6;
  const int b  = bn >> 11;
  const int* id = idx + (size_t)bn*KK;
  float base = bs[t];
  float mx = -INFINITY, mn = INFINITY;
  #pragma unroll
  for(int k=0;k<KK;k++){
    int ik = id[k];
    float v = q[((size_t)((b<<11) + ik))*64 + o];
    mx = fmaxf(mx, v); mn = fminf(mn, v);
  }
  float a  = g[cb+o] * RSQ;
  float bo = bb[cb+o];
  float h  = lrelu((a >= 0.f ? a*(mx+base) : a*(mn+base)) + bo);
  out[(size_t)bn*CFULL + cb + o] = h;
}

// ---------------- head: cat*W5^T with fused max/min over n ----------------
__launch_bounds__(256) __global__ void w5max_k(const float* x1,const float* x2,const float* x3,
    const float* x4, const float* W5T, unsigned* mxe, unsigned* mne){
  __shared__ float cat[16*512];
  __shared__ float redm[512], redn[512];
  const int blk = blockIdx.x;             // 1024 = B * (N/16)
  const int b  = blk >> 7;
  const int r0 = (blk & 127)*16;
  const int t  = threadIdx.x;
  const size_t bn0 = (size_t)b*NN + r0;
  for(int i=t; i<16*512; i+=256){
    int r = i>>9, c = i&511;
    size_t row = bn0 + r;
    float v;
    if(c<64)       v = x1[row*64  + c];
    else if(c<128) v = x2[row*64  + (c-64)];
    else if(c<256) v = x3[row*128 + (c-128)];
    else           v = x4[row*256 + (c-256)];
    cat[i] = v;
  }
  __syncthreads();
  const int half = t>>7, tq = t&127;
  const int rbase = half*8;
  float acc[4][8];
  #pragma unroll
  for(int j=0;j<4;j++){
    #pragma unroll
    for(int r=0;r<8;r++) acc[j][r]=0.f;
  }
  for(int c=0;c<512;c+=4){
    float w[4][4];
    #pragma unroll
    for(int cc=0;cc<4;cc++){
      #pragma unroll
      for(int j=0;j<4;j++) w[cc][j] = W5T[(size_t)(c+cc)*512 + tq + 128*j];
    }
    #pragma unroll
    for(int r=0;r<8;r++){
      float4 cv = *(const float4*)&cat[(rbase+r)*512 + c];
      #pragma unroll
      for(int j=0;j<4;j++)
        acc[j][r] = fmaf(cv.x, w[0][j], fmaf(cv.y, w[1][j], fmaf(cv.z, w[2][j], fmaf(cv.w, w[3][j], acc[j][r]))));
    }
  }
  float lmx[4], lmn[4];
  #pragma unroll
  for(int j=0;j<4;j++){
    float M=-INFINITY, m=INFINITY;
    #pragma unroll
    for(int r=0;r<8;r++){ M=fmaxf(M,acc[j][r]); m=fminf(m,acc[j][r]); }
    lmx[j]=M; lmn[j]=m;
  }
  if(half==0){
    #pragma unroll
    for(int j=0;j<4;j++){ redm[tq+128*j]=lmx[j]; redn[tq+128*j]=lmn[j]; }
  }
  __syncthreads();
  if(half==1){
    #pragma unroll
    for(int j=0;j<4;j++){
      int o = tq + 128*j;
      float M = fmaxf(lmx[j], redm[o]);
      float m = fminf(lmn[j], redn[o]);
      atomicMax(&mxe[b*512+o], encf(M));
      atomicMin(&mne[b*512+o], encf(m));
    }
  }
}

__launch_bounds__(256) __global__ void final_k(const unsigned* mxe, const unsigned* mne,
    const float* g5, const float* b5, const float* Wemb, float* out){
  const int b = blockIdx.x, t = threadIdx.x;
  __shared__ float h[512];
  for(int o=t; o<512; o+=256){
    float mx = decf(mxe[b*512+o]);
    float mn = decf(mne[b*512+o]);
    float a  = g5[o] * RSQ;
    float bo = b5[o];
    float hv = lrelu((a >= 0.f ? a*mx : a*mn) + bo);
    h[o] = hv;
    out[b*512+o] = hv;
  }
  __syncthreads();
  const float* wr = Wemb + (size_t)t*512;
  float s = 0.f;
  for(int o=0;o<512;o+=4){
    float4 w4 = *(const float4*)(wr+o);
    s = fmaf(h[o],w4.x, fmaf(h[o+1],w4.y, fmaf(h[o+2],w4.z, fmaf(h[o+3],w4.w, s))));
  }
  out[4096 + b*256 + t] = s;
}

// ---------------- launch ----------------
extern "C" void kernel_launch(void* const* d_in, const int* in_sizes, int n_in,
                              void* d_out, int out_size, void* d_ws, size_t ws_size,
                              hipStream_t stream) {
  if (ws_size < WS_END * sizeof(float)) return;

  const float* x0   = (const float*)d_in[0];
  const float* W1   = (const float*)d_in[1];
  const float* g1   = (const float*)d_in[2];
  const float* b1   = (const float*)d_in[3];
  const float* W2   = (const float*)d_in[4];
  const float* g2   = (const float*)d_in[5];
  const float* b2   = (const float*)d_in[6];
  const float* W3   = (const float*)d_in[7];
  const float* g3   = (const float*)d_in[8];
  const float* b3   = (const float*)d_in[9];
  const float* W4   = (const float*)d_in[10];
  const float* g4   = (const float*)d_in[11];
  const float* b4   = (const float*)d_in[12];
  const float* W5   = (const float*)d_in[13];
  const float* g5   = (const float*)d_in[14];
  const float* b5   = (const float*)d_in[15];
  const float* Wemb = (const float*)d_in[16];

  float* ws = (float*)d_ws;
  float* xx = ws + OFF_XX;
  float* x1 = ws + OFF_X1;  float* x2 = ws + OFF_X2;
  float* x3 = ws + OFF_X3;  float* x4 = ws + OFF_X4;
  float* q  = ws + OFF_SC;
  float* bs = ws + OFF_SC + (size_t)BN*64;
  int*   id = (int*)(ws + OFF_ID);
  float* W5Tf = ws + OFF_W5T;
  unsigned* mxe = (unsigned*)(ws + OFF_MX);
  unsigned* mne = (unsigned*)(ws + OFF_MN);
  float* distD = ws + OFF_X3;   // dual-batch dist (L1..L3)
  float* distS = ws + OFF_X4;   // single-batch dist (L4)
  float* out = (float*)d_out;

  transposeW5_k<<<262144/256,256,0,stream>>>(W5, W5Tf);
  init_enc_k<<<BB*512/256,256,0,stream>>>(mxe, mne);

  // layer 1 (3 -> 64)
  sqnorm_k<3><<<BN/256,256,0,stream>>>(x0, xx);
  for(int r=0;r<4;r++){
    dist3_k<<<2*NN,256,0,stream>>>(x0, xx, distD, 2*r);
    sel_k<<<(2*NN)/4,256,0,stream>>>(distD, id, 2*r, 2*NN);
  }
  qp64_k<3><<<BN*8/256,256,0,stream>>>(x0, W1, 0, q, bs);
  gather64_k<64><<<BN*64/256,256,0,stream>>>(q, bs, id, g1, b1, 0, x1);

  // layer 2 (64 -> 64)
  sqnorm_k<64><<<BN/256,256,0,stream>>>(x1, xx);
  for(int r=0;r<4;r++){
    gemm_dist_k<64><<<dim3(16,16,2),256,0,stream>>>(x1, xx, distD, 2*r);
    sel_k<<<(2*NN)/4,256,0,stream>>>(distD, id, 2*r, 2*NN);
  }
  qp64_k<64><<<BN*8/256,256,0,stream>>>(x1, W2, 0, q, bs);
  gather64_k<64><<<BN*64/256,256,0,stream>>>(q, bs, id, g2, b2, 0, x2);

  // layer 3 (64 -> 128)
  sqnorm_k<64><<<BN/256,256,0,stream>>>(x2, xx);
  for(int r=0;r<4;r++){
    gemm_dist_k<64><<<dim3(16,16,2),256,0,stream>>>(x2, xx, distD, 2*r);
    sel_k<<<(2*NN)/4,256,0,stream>>>(distD, id, 2*r, 2*NN);
  }
  for(int cb=0; cb<128; cb+=64){
    qp64_k<64><<<BN*8/256,256,0,stream>>>(x2, W3, cb, q, bs);
    gather64_k<128><<<BN*64/256,256,0,stream>>>(q, bs, id, g3, b3, cb, x3);
  }

  // layer 4 (128 -> 256): x3 live -> single-batch dist in x4 region
  sqnorm_k<128><<<BN/256,256,0,stream>>>(x3, xx);
  for(int r=0;r<8;r++){
    gemm_dist_k<128><<<dim3(16,16,1),256,0,stream>>>(x3, xx, distS, r);
    sel_k<<<NN/4,256,0,stream>>>(distS, id, r, NN);
  }
  for(int cb=0; cb<256; cb+=64){
    qp64_k<128><<<BN*8/256,256,0,stream>>>(x3, W4, cb, q, bs);
    gather64_k<256><<<BN*64/256,256,0,stream>>>(q, bs, id, g4, b4, cb, x4);
  }

  // head
  w5max_k<<<BB*(NN/16),256,0,stream>>>(x1, x2, x3, x4, W5Tf, mxe, mne);
  final_k<<<BB,256,0,stream>>>(mxe, mne, g5, b5, Wemb, out);
}

// Round 11
// 1665.281 us; speedup vs baseline: 5.2555x; 1.3208x over previous
//
#include <hip/hip_runtime.h>
#include <hip/hip_bf16.h>

#define BB 8
#define NN 2048
#define KK 20
#define BN (BB*NN)
#define RSQ 0.99999500003749969f   // 1/sqrt(1+1e-5)

// ---------------- workspace layout (float-slot units), 44.7 MiB total ----------------
constexpr size_t OFF_XX  = 0;                          // BN
constexpr size_t OFF_X1  = OFF_XX  + BN;               // BN*64
constexpr size_t OFF_X2  = OFF_X1  + (size_t)BN*64;    // BN*64
constexpr size_t OFF_X3  = OFF_X2  + (size_t)BN*64;    // BN*128
constexpr size_t OFF_X4  = OFF_X3  + (size_t)BN*128;   // BN*256
constexpr size_t OFF_SC  = OFF_X4  + (size_t)BN*256;   // BN*160 (q,bs post-knn)
constexpr size_t OFF_ID  = OFF_SC  + (size_t)BN*160;   // int BN*20
constexpr size_t OFF_W5T = OFF_ID  + (size_t)BN*20;    // 512*512
constexpr size_t OFF_MX  = OFF_W5T + 512*512;
constexpr size_t OFF_MN  = OFF_MX  + BB*512;
constexpr size_t OFF_WT2 = OFF_MN  + BB*512;           // [128][64]
constexpr size_t OFF_WT3 = OFF_WT2 + 8192;             // [128][128]
constexpr size_t OFF_WT4 = OFF_WT3 + 16384;            // [256][256]
constexpr size_t WS_END  = OFF_WT4 + 65536;            // 11,714,560 floats (< 11,895,168 proven)
// dist buffers (time-shared):
//  dual-batch (4096x2048) at OFF_X3 for L2/L3 (x3,x4,SC dead)  ✓
//  single-batch (2048x2048) at OFF_X4 for L4 (x3 live, x4 dead) ✓
static_assert(OFF_ID - OFF_X3 >= (size_t)4096*2048, "dual dist fits");

__device__ inline unsigned encf(float f){ unsigned u=__float_as_uint(f); return (u&0x80000000u)? ~u : (u|0x80000000u); }
__device__ inline float decf(unsigned e){ unsigned u=(e&0x80000000u)? (e&0x7fffffffu) : ~e; return __uint_as_float(u); }
__device__ inline float lrelu(float h){ return h>=0.f ? h : 0.2f*h; }

// ---------------- prep: all weight transposes + enc init, one dispatch ----------------
__global__ void prep_k(const float* W5, const float* W2, const float* W3, const float* W4,
                       float* W5T, float* WT2, float* WT3, float* WT4,
                       unsigned* mx, unsigned* mn){
  int i = blockIdx.x*256 + threadIdx.x;     // grid covers 262144
  { int o = i>>9, c = i&511; W5T[c*512+o] = W5[i]; }
  if(i < 65536){ int o = i>>8, c = i&255; WT4[c*256+o] = W4[i]; }   // W4: 256 x 256
  if(i < 16384){ int o = i>>7, c = i&127; WT3[c*128+o] = W3[i]; }   // W3: 128 x 128
  if(i <  8192){ int o = i>>7, c = i&127; WT2[c*64 +o] = W2[i]; }   // W2: 64 x 128
  if(i <  4096){ mx[i] = 0x007FFFFFu; mn[i] = 0xFF800000u; }
}

// ---------------- KNN ----------------
template<int C>
__launch_bounds__(256) __global__ void sqnorm_k(const float* X, float* xx){
  int i = blockIdx.x*256 + threadIdx.x;   // BN
  const float* r = X + (size_t)i*C;
  float s = 0.f;
  #pragma unroll
  for(int c=0;c<C;c++) s = fmaf(r[c], r[c], s);
  xx[i] = s;
}

#define FMA_ROW(I) \
  acc[I][0]=fmaf(a,b0v,acc[I][0]); acc[I][1]=fmaf(a,b1v,acc[I][1]); \
  acc[I][2]=fmaf(a,b2v,acc[I][2]); acc[I][3]=fmaf(a,b3v,acc[I][3]); \
  acc[I][4]=fmaf(a,b4v,acc[I][4]); acc[I][5]=fmaf(a,b5v,acc[I][5]); \
  acc[I][6]=fmaf(a,b6v,acc[I][6]); acc[I][7]=fmaf(a,b7v,acc[I][7]);

// Pure GEMM distance kernel: 128n x 128m tile, 8x8 micro-tile, writes negd to global.
template<int C>
__launch_bounds__(256) __global__ void gemm_dist_k(const float* __restrict__ X, const float* __restrict__ xx,
                                                   float* __restrict__ dist, int b0){
  constexpr int AST = 188;
  __shared__ __align__(16) float a_sh[16*AST];
  __shared__ __align__(16) float b_sh[16*AST];
  __shared__ float sxn[128], sxm[128];
  const int tid = threadIdx.x;
  const int b   = b0 + blockIdx.z;
  const int mtile = blockIdx.x*128;
  const int ntile = blockIdx.y*128;
  const int tn = tid & 15, tm = tid >> 4;
  const float* Xb  = X  + (size_t)b*NN*C;
  const float* xxb = xx + (size_t)b*NN;
  if(tid < 128) sxn[tid] = xxb[ntile + tid];
  else          sxm[tid-128] = xxb[mtile + tid-128];
  float acc[8][8];
  #pragma unroll
  for(int i=0;i<8;i++){
    #pragma unroll
    for(int j=0;j<8;j++) acc[i][j]=0.f;
  }
  for(int cc=0; cc<C; cc+=16){
    __syncthreads();
    #pragma unroll
    for(int s=0;s<2;s++){
      int ii = tid + 256*s; int r = ii>>2, q = ii&3;
      int pr = r + 4*(r>>3);
      float4 va = *(const float4*)&Xb[(size_t)(ntile + r)*C + cc + 4*q];
      a_sh[(4*q+0)*AST + pr]=va.x; a_sh[(4*q+1)*AST + pr]=va.y;
      a_sh[(4*q+2)*AST + pr]=va.z; a_sh[(4*q+3)*AST + pr]=va.w;
      float4 vb = *(const float4*)&Xb[(size_t)(mtile + r)*C + cc + 4*q];
      b_sh[(4*q+0)*AST + pr]=vb.x; b_sh[(4*q+1)*AST + pr]=vb.y;
      b_sh[(4*q+2)*AST + pr]=vb.z; b_sh[(4*q+3)*AST + pr]=vb.w;
    }
    __syncthreads();
    #pragma unroll
    for(int c=0;c<16;c++){
      float4 A0 = *(const float4*)&a_sh[c*AST + 12*tn];
      float4 A1 = *(const float4*)&a_sh[c*AST + 12*tn + 4];
      float4 B0 = *(const float4*)&b_sh[c*AST + 12*tm];
      float4 B1 = *(const float4*)&b_sh[c*AST + 12*tm + 4];
      float b0v=B0.x,b1v=B0.y,b2v=B0.z,b3v=B0.w,b4v=B1.x,b5v=B1.y,b6v=B1.z,b7v=B1.w;
      float a;
      a=A0.x; FMA_ROW(0)
      a=A0.y; FMA_ROW(1)
      a=A0.z; FMA_ROW(2)
      a=A0.w; FMA_ROW(3)
      a=A1.x; FMA_ROW(4)
      a=A1.y; FMA_ROW(5)
      a=A1.z; FMA_ROW(6)
      a=A1.w; FMA_ROW(7)
    }
  }
  float xnr[8], xmr[8];
  #pragma unroll
  for(int i=0;i<8;i++){ xnr[i]=sxn[tn*8+i]; xmr[i]=sxm[tm*8+i]; }
  const size_t rowb = (size_t)blockIdx.z*NN + ntile + tn*8;
  #pragma unroll
  for(int i=0;i<8;i++){
    float4 w0, w1;
    w0.x=(2.f*acc[i][0]-xnr[i])-xmr[0]; w0.y=(2.f*acc[i][1]-xnr[i])-xmr[1];
    w0.z=(2.f*acc[i][2]-xnr[i])-xmr[2]; w0.w=(2.f*acc[i][3]-xnr[i])-xmr[3];
    w1.x=(2.f*acc[i][4]-xnr[i])-xmr[4]; w1.y=(2.f*acc[i][5]-xnr[i])-xmr[5];
    w1.z=(2.f*acc[i][6]-xnr[i])-xmr[6]; w1.w=(2.f*acc[i][7]-xnr[i])-xmr[7];
    float* dp = dist + (rowb + i)*NN + mtile + tm*8;
    *(float4*)dp = w0;
    *(float4*)(dp+4) = w1;
  }
}

// Wave-cooperative top-20 (sorted in lanes 0..19), reading materialized dist rows.
__launch_bounds__(256) __global__ void sel_k(const float* __restrict__ dist, int* __restrict__ id,
                                             int b0, int nrows){
  const int w = (blockIdx.x*256 + threadIdx.x) >> 6;
  const int lane = threadIdx.x & 63;
  if(w >= nrows) return;
  const float* dr = dist + (size_t)w*NN;
  float lv = -INFINITY; int li = 0;
  float theta = -INFINITY;
  for(int ms=0; ms<NN; ms+=64){
    float cand = dr[ms + lane];
    unsigned long long bal = __ballot(cand > theta);
    while(bal){
      int bpos = __ffsll((unsigned long long)bal) - 1;
      bal &= bal - 1;
      float cv = __shfl(cand, bpos);
      if(cv > theta){
        int ci = ms + bpos;
        unsigned long long mge = __ballot(lv >= cv);
        int pos = __popcll(mge);
        float upv = __shfl_up(lv, 1);
        int   upi = __shfl_up(li, 1);
        bool shift = (lane > pos) && (lane < KK);
        lv = (lane == pos) ? cv : (shift ? upv : lv);
        li = (lane == pos) ? ci : (shift ? upi : li);
        theta = __shfl(lv, KK-1);
      }
    }
  }
  if(lane < KK) id[((size_t)b0*NN + w)*KK + lane] = li;
}

// L1 fused: wave per n-row, computes C=3 distances inline (same fmaf order as dist3).
__launch_bounds__(256) __global__ void sel3_k(const float* __restrict__ X, const float* __restrict__ xx,
                                              int* __restrict__ id){
  const int gw = (blockIdx.x*256 + threadIdx.x) >> 6;   // row = global bn
  const int lane = threadIdx.x & 63;
  const int b = gw >> 11, n = gw & 2047;
  const float* Xb  = X + (size_t)b*NN*3;
  const float* xxb = xx + (size_t)b*NN;
  const float x0v = Xb[n*3], x1v = Xb[n*3+1], x2v = Xb[n*3+2];
  const float xxn = xxb[n];
  float lv = -INFINITY; int li = 0;
  float theta = -INFINITY;
  for(int ms=0; ms<NN; ms+=64){
    int m = ms + lane;
    float s = 0.f;
    s = fmaf(x0v, Xb[m*3+0], s);
    s = fmaf(x1v, Xb[m*3+1], s);
    s = fmaf(x2v, Xb[m*3+2], s);
    float cand = (2.f*s - xxn) - xxb[m];
    unsigned long long bal = __ballot(cand > theta);
    while(bal){
      int bpos = __ffsll((unsigned long long)bal) - 1;
      bal &= bal - 1;
      float cv = __shfl(cand, bpos);
      if(cv > theta){
        int ci = ms + bpos;
        unsigned long long mge = __ballot(lv >= cv);
        int pos = __popcll(mge);
        float upv = __shfl_up(lv, 1);
        int   upi = __shfl_up(li, 1);
        bool shift = (lane > pos) && (lane < KK);
        lv = (lane == pos) ? cv : (shift ? upv : lv);
        li = (lane == pos) ? ci : (shift ? upi : li);
        theta = __shfl(lv, KK-1);
      }
    }
  }
  if(lane < KK) id[(size_t)gw*KK + lane] = li;
}

// ---------------- qp ----------------
// L1 only (CIN=3): small weights, old style
__launch_bounds__(256) __global__ void qp3_k(const float* X, const float* W,
                                             float* q, float* bs){
  const int t   = blockIdx.x*256 + threadIdx.x;  // BN*8
  const int row = t >> 3;
  const int c0  = (t & 7) * 8;
  float xn[3];
  #pragma unroll
  for(int c=0;c<3;c++) xn[c] = X[(size_t)row*3 + c];
  for(int oi=c0; oi<c0+8; oi++){
    const float* w = W + (size_t)oi*6;
    float aq=0.f, ap=0.f;
    #pragma unroll
    for(int c=0;c<3;c++){ aq = fmaf(xn[c], w[c], aq); ap = fmaf(xn[c], w[3+c], ap); }
    q [(size_t)row*64 + oi] = aq;
    bs[(size_t)row*64 + oi] = ap - aq;
  }
}

// Transposed-weight qp: WT is [2*CIN][COUT]; loads are broadcast-coalesced float4.
template<int CIN, int COUT>
__launch_bounds__(256) __global__ void qp64T_k(const float* __restrict__ X, const float* __restrict__ WT,
                                               int cb, float* __restrict__ q, float* __restrict__ bs){
  const int t   = blockIdx.x*256 + threadIdx.x;  // BN*8
  const int row = t >> 3;
  const int o0  = cb + (t & 7) * 8;
  float xn[CIN];
  #pragma unroll
  for(int c=0;c<CIN;c+=4){ float4 v = *(const float4*)(X + (size_t)row*CIN + c);
    xn[c]=v.x; xn[c+1]=v.y; xn[c+2]=v.z; xn[c+3]=v.w; }
  float aq[8], ap[8];
  #pragma unroll
  for(int j=0;j<8;j++){ aq[j]=0.f; ap[j]=0.f; }
  #pragma unroll 4
  for(int c=0;c<CIN;c++){
    float xc = xn[c];
    float4 wa0 = *(const float4*)&WT[(size_t)c*COUT + o0];
    float4 wa1 = *(const float4*)&WT[(size_t)c*COUT + o0 + 4];
    float4 wb0 = *(const float4*)&WT[(size_t)(CIN+c)*COUT + o0];
    float4 wb1 = *(const float4*)&WT[(size_t)(CIN+c)*COUT + o0 + 4];
    aq[0]=fmaf(xc,wa0.x,aq[0]); aq[1]=fmaf(xc,wa0.y,aq[1]); aq[2]=fmaf(xc,wa0.z,aq[2]); aq[3]=fmaf(xc,wa0.w,aq[3]);
    aq[4]=fmaf(xc,wa1.x,aq[4]); aq[5]=fmaf(xc,wa1.y,aq[5]); aq[6]=fmaf(xc,wa1.z,aq[6]); aq[7]=fmaf(xc,wa1.w,aq[7]);
    ap[0]=fmaf(xc,wb0.x,ap[0]); ap[1]=fmaf(xc,wb0.y,ap[1]); ap[2]=fmaf(xc,wb0.z,ap[2]); ap[3]=fmaf(xc,wb0.w,ap[3]);
    ap[4]=fmaf(xc,wb1.x,ap[4]); ap[5]=fmaf(xc,wb1.y,ap[5]); ap[6]=fmaf(xc,wb1.z,ap[6]); ap[7]=fmaf(xc,wb1.w,ap[7]);
  }
  float4 q0 = make_float4(aq[0],aq[1],aq[2],aq[3]);
  float4 q1 = make_float4(aq[4],aq[5],aq[6],aq[7]);
  float4 b0 = make_float4(ap[0]-aq[0],ap[1]-aq[1],ap[2]-aq[2],ap[3]-aq[3]);
  float4 b1 = make_float4(ap[4]-aq[4],ap[5]-aq[5],ap[6]-aq[6],ap[7]-aq[7]);
  float* qp = q  + (size_t)row*64 + (o0-cb);
  float* bp = bs + (size_t)row*64 + (o0-cb);
  *(float4*)qp = q0; *(float4*)(qp+4) = q1;
  *(float4*)bp = b0; *(float4*)(bp+4) = b1;
}

template<int CFULL>
__launch_bounds__(256) __global__ void gather64_k(const float* q, const float* bs, const int* idx,
    const float* g, const float* bb, int cb, float* out){
  const int t  = blockIdx.x*256 + threadIdx.x;   // BN*64
  const int o  = t & 63;
  const int bn = t >> 6;
  const int b  = bn >> 11;
  const int* id = idx + (size_t)bn*KK;
  float base = bs[t];
  float mx = -INFINITY, mn = INFINITY;
  #pragma unroll
  for(int k=0;k<KK;k++){
    int ik = id[k];
    float v = q[((size_t)((b<<11) + ik))*64 + o];
    mx = fmaxf(mx, v); mn = fminf(mn, v);
  }
  float a  = g[cb+o] * RSQ;
  float bo = bb[cb+o];
  float h  = lrelu((a >= 0.f ? a*(mx+base) : a*(mn+base)) + bo);
  out[(size_t)bn*CFULL + cb + o] = h;
}

// ---------------- head: cat*W5^T with fused max/min over n ----------------
// v2: 128 threads, thread = 8 rows x 8 cols. cat reads wave-uniform (broadcast, free);
// W5T reads 2x float4 per c (coalesced). LDS demand per FMA 4x lower than v1.
__launch_bounds__(128) __global__ void w5max_k(const float* x1,const float* x2,const float* x3,
    const float* x4, const float* W5T, unsigned* mxe, unsigned* mne){
  __shared__ float cat[16*512];
  __shared__ float redm[512], redn[512];
  const int blk = blockIdx.x;             // 1024 = B * (N/16)
  const int b  = blk >> 7;
  const int r0 = (blk & 127)*16;
  const int t  = threadIdx.x;             // 128
  const size_t bn0 = (size_t)b*NN + r0;
  for(int i=t; i<16*512; i+=128){
    int r = i>>9, c = i&511;
    size_t row = bn0 + r;
    float v;
    if(c<64)       v = x1[row*64  + c];
    else if(c<128) v = x2[row*64  + (c-64)];
    else if(c<256) v = x3[row*128 + (c-128)];
    else           v = x4[row*256 + (c-256)];
    cat[i] = v;
  }
  __syncthreads();
  const int og = t & 63;          // o-block: cols og*8 .. og*8+7
  const int rg = t >> 6;          // row-group: rows rg*8 .. rg*8+7
  const int o0 = og*8;
  float acc[8][8];                // [row][col]
  #pragma unroll
  for(int r=0;r<8;r++){
    #pragma unroll
    for(int j=0;j<8;j++) acc[r][j]=0.f;
  }
  for(int c=0;c<512;c+=4){
    float w[4][8];
    #pragma unroll
    for(int cc=0;cc<4;cc++){
      float4 wa = *(const float4*)&W5T[(size_t)(c+cc)*512 + o0];
      float4 wb = *(const float4*)&W5T[(size_t)(c+cc)*512 + o0 + 4];
      w[cc][0]=wa.x; w[cc][1]=wa.y; w[cc][2]=wa.z; w[cc][3]=wa.w;
      w[cc][4]=wb.x; w[cc][5]=wb.y; w[cc][6]=wb.z; w[cc][7]=wb.w;
    }
    #pragma unroll
    for(int r=0;r<8;r++){
      float4 cv = *(const float4*)&cat[(rg*8+r)*512 + c];   // wave-uniform -> broadcast
      #pragma unroll
      for(int j=0;j<8;j++)
        acc[r][j] = fmaf(cv.x, w[0][j], fmaf(cv.y, w[1][j], fmaf(cv.z, w[2][j], fmaf(cv.w, w[3][j], acc[r][j]))));
    }
  }
  float lmx[8], lmn[8];
  #pragma unroll
  for(int j=0;j<8;j++){
    float M=-INFINITY, m=INFINITY;
    #pragma unroll
    for(int r=0;r<8;r++){ M=fmaxf(M,acc[r][j]); m=fminf(m,acc[r][j]); }
    lmx[j]=M; lmn[j]=m;
  }
  if(rg==0){
    #pragma unroll
    for(int j=0;j<8;j++){ redm[o0+j]=lmx[j]; redn[o0+j]=lmn[j]; }
  }
  __syncthreads();
  if(rg==1){
    #pragma unroll
    for(int j=0;j<8;j++){
      int o = o0 + j;
      float M = fmaxf(lmx[j], redm[o]);
      float m = fminf(lmn[j], redn[o]);
      atomicMax(&mxe[b*512+o], encf(M));
      atomicMin(&mne[b*512+o], encf(m));
    }
  }
}

__launch_bounds__(256) __global__ void final_k(const unsigned* mxe, const unsigned* mne,
    const float* g5, const float* b5, const float* Wemb, float* out){
  const int b = blockIdx.x, t = threadIdx.x;
  __shared__ float h[512];
  for(int o=t; o<512; o+=256){
    float mx = decf(mxe[b*512+o]);
    float mn = decf(mne[b*512+o]);
    float a  = g5[o] * RSQ;
    float bo = b5[o];
    float hv = lrelu((a >= 0.f ? a*mx : a*mn) + bo);
    h[o] = hv;
    out[b*512+o] = hv;
  }
  __syncthreads();
  const float* wr = Wemb + (size_t)t*512;
  float s = 0.f;
  for(int o=0;o<512;o+=4){
    float4 w4 = *(const float4*)(wr+o);
    s = fmaf(h[o],w4.x, fmaf(h[o+1],w4.y, fmaf(h[o+2],w4.z, fmaf(h[o+3],w4.w, s))));
  }
  out[4096 + b*256 + t] = s;
}

// ---------------- launch ----------------
extern "C" void kernel_launch(void* const* d_in, const int* in_sizes, int n_in,
                              void* d_out, int out_size, void* d_ws, size_t ws_size,
                              hipStream_t stream) {
  if (ws_size < WS_END * sizeof(float)) return;

  const float* x0   = (const float*)d_in[0];
  const float* W1   = (const float*)d_in[1];
  const float* g1   = (const float*)d_in[2];
  const float* b1   = (const float*)d_in[3];
  const float* W2   = (const float*)d_in[4];
  const float* g2   = (const float*)d_in[5];
  const float* b2   = (const float*)d_in[6];
  const float* W3   = (const float*)d_in[7];
  const float* g3   = (const float*)d_in[8];
  const float* b3   = (const float*)d_in[9];
  const float* W4   = (const float*)d_in[10];
  const float* g4   = (const float*)d_in[11];
  const float* b4   = (const float*)d_in[12];
  const float* W5   = (const float*)d_in[13];
  const float* g5   = (const float*)d_in[14];
  const float* b5   = (const float*)d_in[15];
  const float* Wemb = (const float*)d_in[16];

  float* ws = (float*)d_ws;
  float* xx = ws + OFF_XX;
  float* x1 = ws + OFF_X1;  float* x2 = ws + OFF_X2;
  float* x3 = ws + OFF_X3;  float* x4 = ws + OFF_X4;
  float* q  = ws + OFF_SC;
  float* bs = ws + OFF_SC + (size_t)BN*64;
  int*   id = (int*)(ws + OFF_ID);
  float* W5Tf = ws + OFF_W5T;
  unsigned* mxe = (unsigned*)(ws + OFF_MX);
  unsigned* mne = (unsigned*)(ws + OFF_MN);
  float* WT2 = ws + OFF_WT2;
  float* WT3 = ws + OFF_WT3;
  float* WT4 = ws + OFF_WT4;
  float* distD = ws + OFF_X3;   // dual-batch dist (L2/L3)
  float* distS = ws + OFF_X4;   // single-batch dist (L4)
  float* out = (float*)d_out;

  prep_k<<<1024,256,0,stream>>>(W5, W2, W3, W4, W5Tf, WT2, WT3, WT4, mxe, mne);

  // layer 1 (3 -> 64): fused inline-distance selection, 1 dispatch
  sqnorm_k<3><<<BN/256,256,0,stream>>>(x0, xx);
  sel3_k<<<BN*64/256,256,0,stream>>>(x0, xx, id);
  qp3_k<<<BN*8/256,256,0,stream>>>(x0, W1, q, bs);
  gather64_k<64><<<BN*64/256,256,0,stream>>>(q, bs, id, g1, b1, 0, x1);

  // layer 2 (64 -> 64)
  sqnorm_k<64><<<BN/256,256,0,stream>>>(x1, xx);
  for(int r=0;r<4;r++){
    gemm_dist_k<64><<<dim3(16,16,2),256,0,stream>>>(x1, xx, distD, 2*r);
    sel_k<<<(2*NN)/4,256,0,stream>>>(distD, id, 2*r, 2*NN);
  }
  qp64T_k<64,64><<<BN*8/256,256,0,stream>>>(x1, WT2, 0, q, bs);
  gather64_k<64><<<BN*64/256,256,0,stream>>>(q, bs, id, g2, b2, 0, x2);

  // layer 3 (64 -> 128)
  sqnorm_k<64><<<BN/256,256,0,stream>>>(x2, xx);
  for(int r=0;r<4;r++){
    gemm_dist_k<64><<<dim3(16,16,2),256,0,stream>>>(x2, xx, distD, 2*r);
    sel_k<<<(2*NN)/4,256,0,stream>>>(distD, id, 2*r, 2*NN);
  }
  for(int cb=0; cb<128; cb+=64){
    qp64T_k<64,128><<<BN*8/256,256,0,stream>>>(x2, WT3, cb, q, bs);
    gather64_k<128><<<BN*64/256,256,0,stream>>>(q, bs, id, g3, b3, cb, x3);
  }

  // layer 4 (128 -> 256): x3 live -> single-batch dist in x4 region
  sqnorm_k<128><<<BN/256,256,0,stream>>>(x3, xx);
  for(int r=0;r<8;r++){
    gemm_dist_k<128><<<dim3(16,16,1),256,0,stream>>>(x3, xx, distS, r);
    sel_k<<<NN/4,256,0,stream>>>(distS, id, r, NN);
  }
  for(int cb=0; cb<256; cb+=64){
    qp64T_k<128,256><<<BN*8/256,256,0,stream>>>(x3, WT4, cb, q, bs);
    gather64_k<256><<<BN*64/256,256,0,stream>>>(q, bs, id, g4, b4, cb, x4);
  }

  // head
  w5max_k<<<BB*(NN/16),128,0,stream>>>(x1, x2, x3, x4, W5Tf, mxe, mne);
  final_k<<<BB,256,0,stream>>>(mxe, mne, g5, b5, Wemb, out);
}

// Round 12
// 1249.955 us; speedup vs baseline: 7.0018x; 1.3323x over previous
//
#include <hip/hip_runtime.h>
#include <hip/hip_bf16.h>

#define BB 8
#define NN 2048
#define KK 20
#define BN (BB*NN)
#define RSQ 0.99999500003749969f   // 1/sqrt(1+1e-5)

// ---------------- workspace layout (float-slot units), 44.7 MiB baseline ----------------
constexpr size_t OFF_XX  = 0;                          // BN
constexpr size_t OFF_X1  = OFF_XX  + BN;               // BN*64
constexpr size_t OFF_X2  = OFF_X1  + (size_t)BN*64;    // BN*64
constexpr size_t OFF_X3  = OFF_X2  + (size_t)BN*64;    // BN*128
constexpr size_t OFF_X4  = OFF_X3  + (size_t)BN*128;   // BN*256
constexpr size_t OFF_SC  = OFF_X4  + (size_t)BN*256;   // BN*160 (q,bs post-knn)
constexpr size_t OFF_ID  = OFF_SC  + (size_t)BN*160;   // int BN*20
constexpr size_t OFF_W5T = OFF_ID  + (size_t)BN*20;    // 512*512
constexpr size_t OFF_MX  = OFF_W5T + 512*512;
constexpr size_t OFF_MN  = OFF_MX  + BB*512;
constexpr size_t OFF_WT2 = OFF_MN  + BB*512;           // [128][64]
constexpr size_t OFF_WT3 = OFF_WT2 + 8192;             // [128][128]
constexpr size_t OFF_WT4 = OFF_WT3 + 16384;            // [256][256]
constexpr size_t WS_END  = OFF_WT4 + 65536;            // 11,714,560 floats
// big-dist (probed at runtime): full 8-batch dist appended
constexpr size_t OFF_BIG = WS_END;
constexpr size_t WS_BIG_END = OFF_BIG + (size_t)BB*NN*NN;   // +33.55M floats -> 172.7 MiB
// fallback dist buffers (time-shared), as R11:
static_assert(OFF_ID - OFF_X3 >= (size_t)4096*2048, "dual dist fits");

__device__ inline unsigned encf(float f){ unsigned u=__float_as_uint(f); return (u&0x80000000u)? ~u : (u|0x80000000u); }
__device__ inline float decf(unsigned e){ unsigned u=(e&0x80000000u)? (e&0x7fffffffu) : ~e; return __uint_as_float(u); }
__device__ inline float lrelu(float h){ return h>=0.f ? h : 0.2f*h; }

// ---------------- prep ----------------
__global__ void prep_k(const float* W5, const float* W2, const float* W3, const float* W4,
                       float* W5T, float* WT2, float* WT3, float* WT4,
                       unsigned* mx, unsigned* mn){
  int i = blockIdx.x*256 + threadIdx.x;     // 262144
  { int o = i>>9, c = i&511; W5T[c*512+o] = W5[i]; }
  if(i < 65536){ int o = i>>8, c = i&255; WT4[c*256+o] = W4[i]; }
  if(i < 16384){ int o = i>>7, c = i&127; WT3[c*128+o] = W3[i]; }
  if(i <  8192){ int o = i>>7, c = i&127; WT2[c*64 +o] = W2[i]; }
  if(i <  4096){ mx[i] = 0x007FFFFFu; mn[i] = 0xFF800000u; }
}

// ---------------- KNN ----------------
template<int C>
__launch_bounds__(256) __global__ void sqnorm_k(const float* X, float* xx){
  int i = blockIdx.x*256 + threadIdx.x;   // BN
  const float* r = X + (size_t)i*C;
  float s = 0.f;
  #pragma unroll
  for(int c=0;c<C;c++) s = fmaf(r[c], r[c], s);
  xx[i] = s;
}

#define FMA_ROW(I) \
  acc[I][0]=fmaf(a,b0v,acc[I][0]); acc[I][1]=fmaf(a,b1v,acc[I][1]); \
  acc[I][2]=fmaf(a,b2v,acc[I][2]); acc[I][3]=fmaf(a,b3v,acc[I][3]); \
  acc[I][4]=fmaf(a,b4v,acc[I][4]); acc[I][5]=fmaf(a,b5v,acc[I][5]); \
  acc[I][6]=fmaf(a,b6v,acc[I][6]); acc[I][7]=fmaf(a,b7v,acc[I][7]);

template<int C>
__launch_bounds__(256) __global__ void gemm_dist_k(const float* __restrict__ X, const float* __restrict__ xx,
                                                   float* __restrict__ dist, int b0){
  constexpr int AST = 188;
  __shared__ __align__(16) float a_sh[16*AST];
  __shared__ __align__(16) float b_sh[16*AST];
  __shared__ float sxn[128], sxm[128];
  const int tid = threadIdx.x;
  const int b   = b0 + blockIdx.z;
  const int mtile = blockIdx.x*128;
  const int ntile = blockIdx.y*128;
  const int tn = tid & 15, tm = tid >> 4;
  const float* Xb  = X  + (size_t)b*NN*C;
  const float* xxb = xx + (size_t)b*NN;
  if(tid < 128) sxn[tid] = xxb[ntile + tid];
  else          sxm[tid-128] = xxb[mtile + tid-128];
  float acc[8][8];
  #pragma unroll
  for(int i=0;i<8;i++){
    #pragma unroll
    for(int j=0;j<8;j++) acc[i][j]=0.f;
  }
  for(int cc=0; cc<C; cc+=16){
    __syncthreads();
    #pragma unroll
    for(int s=0;s<2;s++){
      int ii = tid + 256*s; int r = ii>>2, q = ii&3;
      int pr = r + 4*(r>>3);
      float4 va = *(const float4*)&Xb[(size_t)(ntile + r)*C + cc + 4*q];
      a_sh[(4*q+0)*AST + pr]=va.x; a_sh[(4*q+1)*AST + pr]=va.y;
      a_sh[(4*q+2)*AST + pr]=va.z; a_sh[(4*q+3)*AST + pr]=va.w;
      float4 vb = *(const float4*)&Xb[(size_t)(mtile + r)*C + cc + 4*q];
      b_sh[(4*q+0)*AST + pr]=vb.x; b_sh[(4*q+1)*AST + pr]=vb.y;
      b_sh[(4*q+2)*AST + pr]=vb.z; b_sh[(4*q+3)*AST + pr]=vb.w;
    }
    __syncthreads();
    #pragma unroll
    for(int c=0;c<16;c++){
      float4 A0 = *(const float4*)&a_sh[c*AST + 12*tn];
      float4 A1 = *(const float4*)&a_sh[c*AST + 12*tn + 4];
      float4 B0 = *(const float4*)&b_sh[c*AST + 12*tm];
      float4 B1 = *(const float4*)&b_sh[c*AST + 12*tm + 4];
      float b0v=B0.x,b1v=B0.y,b2v=B0.z,b3v=B0.w,b4v=B1.x,b5v=B1.y,b6v=B1.z,b7v=B1.w;
      float a;
      a=A0.x; FMA_ROW(0)
      a=A0.y; FMA_ROW(1)
      a=A0.z; FMA_ROW(2)
      a=A0.w; FMA_ROW(3)
      a=A1.x; FMA_ROW(4)
      a=A1.y; FMA_ROW(5)
      a=A1.z; FMA_ROW(6)
      a=A1.w; FMA_ROW(7)
    }
  }
  float xnr[8], xmr[8];
  #pragma unroll
  for(int i=0;i<8;i++){ xnr[i]=sxn[tn*8+i]; xmr[i]=sxm[tm*8+i]; }
  const size_t rowb = (size_t)blockIdx.z*NN + ntile + tn*8;
  #pragma unroll
  for(int i=0;i<8;i++){
    float4 w0, w1;
    w0.x=(2.f*acc[i][0]-xnr[i])-xmr[0]; w0.y=(2.f*acc[i][1]-xnr[i])-xmr[1];
    w0.z=(2.f*acc[i][2]-xnr[i])-xmr[2]; w0.w=(2.f*acc[i][3]-xnr[i])-xmr[3];
    w1.x=(2.f*acc[i][4]-xnr[i])-xmr[4]; w1.y=(2.f*acc[i][5]-xnr[i])-xmr[5];
    w1.z=(2.f*acc[i][6]-xnr[i])-xmr[6]; w1.w=(2.f*acc[i][7]-xnr[i])-xmr[7];
    float* dp = dist + (rowb + i)*NN + mtile + tm*8;
    *(float4*)dp = w0;
    *(float4*)(dp+4) = w1;
  }
}

// Wave-cooperative top-20 (sorted in lanes 0..19)
__launch_bounds__(256) __global__ void sel_k(const float* __restrict__ dist, int* __restrict__ id,
                                             int b0, int nrows){
  const int w = (blockIdx.x*256 + threadIdx.x) >> 6;
  const int lane = threadIdx.x & 63;
  if(w >= nrows) return;
  const float* dr = dist + (size_t)w*NN;
  float lv = -INFINITY; int li = 0;
  float theta = -INFINITY;
  for(int ms=0; ms<NN; ms+=64){
    float cand = dr[ms + lane];
    unsigned long long bal = __ballot(cand > theta);
    while(bal){
      int bpos = __ffsll((unsigned long long)bal) - 1;
      bal &= bal - 1;
      float cv = __shfl(cand, bpos);
      if(cv > theta){
        int ci = ms + bpos;
        unsigned long long mge = __ballot(lv >= cv);
        int pos = __popcll(mge);
        float upv = __shfl_up(lv, 1);
        int   upi = __shfl_up(li, 1);
        bool shift = (lane > pos) && (lane < KK);
        lv = (lane == pos) ? cv : (shift ? upv : lv);
        li = (lane == pos) ? ci : (shift ? upi : li);
        theta = __shfl(lv, KK-1);
      }
    }
  }
  if(lane < KK) id[((size_t)b0*NN + w)*KK + lane] = li;
}

// L1 fused inline-distance selection
__launch_bounds__(256) __global__ void sel3_k(const float* __restrict__ X, const float* __restrict__ xx,
                                              int* __restrict__ id){
  const int gw = (blockIdx.x*256 + threadIdx.x) >> 6;
  const int lane = threadIdx.x & 63;
  const int b = gw >> 11, n = gw & 2047;
  const float* Xb  = X + (size_t)b*NN*3;
  const float* xxb = xx + (size_t)b*NN;
  const float x0v = Xb[n*3], x1v = Xb[n*3+1], x2v = Xb[n*3+2];
  const float xxn = xxb[n];
  float lv = -INFINITY; int li = 0;
  float theta = -INFINITY;
  for(int ms=0; ms<NN; ms+=64){
    int m = ms + lane;
    float s = 0.f;
    s = fmaf(x0v, Xb[m*3+0], s);
    s = fmaf(x1v, Xb[m*3+1], s);
    s = fmaf(x2v, Xb[m*3+2], s);
    float cand = (2.f*s - xxn) - xxb[m];
    unsigned long long bal = __ballot(cand > theta);
    while(bal){
      int bpos = __ffsll((unsigned long long)bal) - 1;
      bal &= bal - 1;
      float cv = __shfl(cand, bpos);
      if(cv > theta){
        int ci = ms + bpos;
        unsigned long long mge = __ballot(lv >= cv);
        int pos = __popcll(mge);
        float upv = __shfl_up(lv, 1);
        int   upi = __shfl_up(li, 1);
        bool shift = (lane > pos) && (lane < KK);
        lv = (lane == pos) ? cv : (shift ? upv : lv);
        li = (lane == pos) ? ci : (shift ? upi : li);
        theta = __shfl(lv, KK-1);
      }
    }
  }
  if(lane < KK) id[(size_t)gw*KK + lane] = li;
}

// ---------------- qp ----------------
__launch_bounds__(256) __global__ void qp3_k(const float* X, const float* W,
                                             float* q, float* bs){
  const int t   = blockIdx.x*256 + threadIdx.x;
  const int row = t >> 3;
  const int c0  = (t & 7) * 8;
  float xn[3];
  #pragma unroll
  for(int c=0;c<3;c++) xn[c] = X[(size_t)row*3 + c];
  for(int oi=c0; oi<c0+8; oi++){
    const float* w = W + (size_t)oi*6;
    float aq=0.f, ap=0.f;
    #pragma unroll
    for(int c=0;c<3;c++){ aq = fmaf(xn[c], w[c], aq); ap = fmaf(xn[c], w[3+c], ap); }
    q [(size_t)row*64 + oi] = aq;
    bs[(size_t)row*64 + oi] = ap - aq;
  }
}

template<int CIN, int COUT>
__launch_bounds__(256) __global__ void qp64T_k(const float* __restrict__ X, const float* __restrict__ WT,
                                               int cb, float* __restrict__ q, float* __restrict__ bs){
  const int t   = blockIdx.x*256 + threadIdx.x;
  const int row = t >> 3;
  const int o0  = cb + (t & 7) * 8;
  float xn[CIN];
  #pragma unroll
  for(int c=0;c<CIN;c+=4){ float4 v = *(const float4*)(X + (size_t)row*CIN + c);
    xn[c]=v.x; xn[c+1]=v.y; xn[c+2]=v.z; xn[c+3]=v.w; }
  float aq[8], ap[8];
  #pragma unroll
  for(int j=0;j<8;j++){ aq[j]=0.f; ap[j]=0.f; }
  #pragma unroll 4
  for(int c=0;c<CIN;c++){
    float xc = xn[c];
    float4 wa0 = *(const float4*)&WT[(size_t)c*COUT + o0];
    float4 wa1 = *(const float4*)&WT[(size_t)c*COUT + o0 + 4];
    float4 wb0 = *(const float4*)&WT[(size_t)(CIN+c)*COUT + o0];
    float4 wb1 = *(const float4*)&WT[(size_t)(CIN+c)*COUT + o0 + 4];
    aq[0]=fmaf(xc,wa0.x,aq[0]); aq[1]=fmaf(xc,wa0.y,aq[1]); aq[2]=fmaf(xc,wa0.z,aq[2]); aq[3]=fmaf(xc,wa0.w,aq[3]);
    aq[4]=fmaf(xc,wa1.x,aq[4]); aq[5]=fmaf(xc,wa1.y,aq[5]); aq[6]=fmaf(xc,wa1.z,aq[6]); aq[7]=fmaf(xc,wa1.w,aq[7]);
    ap[0]=fmaf(xc,wb0.x,ap[0]); ap[1]=fmaf(xc,wb0.y,ap[1]); ap[2]=fmaf(xc,wb0.z,ap[2]); ap[3]=fmaf(xc,wb0.w,ap[3]);
    ap[4]=fmaf(xc,wb1.x,ap[4]); ap[5]=fmaf(xc,wb1.y,ap[5]); ap[6]=fmaf(xc,wb1.z,ap[6]); ap[7]=fmaf(xc,wb1.w,ap[7]);
  }
  float4 q0 = make_float4(aq[0],aq[1],aq[2],aq[3]);
  float4 q1 = make_float4(aq[4],aq[5],aq[6],aq[7]);
  float4 b0 = make_float4(ap[0]-aq[0],ap[1]-aq[1],ap[2]-aq[2],ap[3]-aq[3]);
  float4 b1 = make_float4(ap[4]-aq[4],ap[5]-aq[5],ap[6]-aq[6],ap[7]-aq[7]);
  float* qp = q  + (size_t)row*64 + (o0-cb);
  float* bp = bs + (size_t)row*64 + (o0-cb);
  *(float4*)qp = q0; *(float4*)(qp+4) = q1;
  *(float4*)bp = b0; *(float4*)(bp+4) = b1;
}

template<int CFULL>
__launch_bounds__(256) __global__ void gather64_k(const float* q, const float* bs, const int* idx,
    const float* g, const float* bb, int cb, float* out){
  const int t  = blockIdx.x*256 + threadIdx.x;
  const int o  = t & 63;
  const int bn = t >> 6;
  const int b  = bn >> 11;
  const int* id = idx + (size_t)bn*KK;
  float base = bs[t];
  float mx = -INFINITY, mn = INFINITY;
  #pragma unroll
  for(int k=0;k<KK;k++){
    int ik = id[k];
    float v = q[((size_t)((b<<11) + ik))*64 + o];
    mx = fmaxf(mx, v); mn = fminf(mn, v);
  }
  float a  = g[cb+o] * RSQ;
  float bo = bb[cb+o];
  float h  = lrelu((a >= 0.f ? a*(mx+base) : a*(mn+base)) + bo);
  out[(size_t)bn*CFULL + cb + o] = h;
}

// ---------------- head ----------------
// v2 + w register double-buffer (even/odd): W5T loads for step c4+1 issue before
// computing step c4 -> 512 FMA cycles hide the ~200-cyc L2 latency. Bit-exact.
#define W5_LOAD(WBUF, CIDX) { \
  int c_ = (CIDX)*4; \
  _Pragma("unroll") \
  for(int cc=0;cc<4;cc++){ \
    float4 wa = *(const float4*)&W5T[(size_t)(c_+cc)*512 + o0]; \
    float4 wb = *(const float4*)&W5T[(size_t)(c_+cc)*512 + o0 + 4]; \
    WBUF[cc][0]=wa.x; WBUF[cc][1]=wa.y; WBUF[cc][2]=wa.z; WBUF[cc][3]=wa.w; \
    WBUF[cc][4]=wb.x; WBUF[cc][5]=wb.y; WBUF[cc][6]=wb.z; WBUF[cc][7]=wb.w; } }

#define W5_COMPUTE(WBUF, CIDX) { \
  int c_ = (CIDX)*4; \
  _Pragma("unroll") \
  for(int r=0;r<8;r++){ \
    float4 cv = *(const float4*)&cat[(rg*8+r)*512 + c_]; \
    _Pragma("unroll") \
    for(int j=0;j<8;j++) \
      acc[r][j] = fmaf(cv.x, WBUF[0][j], fmaf(cv.y, WBUF[1][j], fmaf(cv.z, WBUF[2][j], fmaf(cv.w, WBUF[3][j], acc[r][j])))); } }

__launch_bounds__(128) __global__ void w5max_k(const float* x1,const float* x2,const float* x3,
    const float* x4, const float* W5T, unsigned* mxe, unsigned* mne){
  __shared__ float cat[16*512];
  __shared__ float redm[512], redn[512];
  const int blk = blockIdx.x;             // 1024
  const int b  = blk >> 7;
  const int r0 = (blk & 127)*16;
  const int t  = threadIdx.x;             // 128
  const size_t bn0 = (size_t)b*NN + r0;
  for(int i=t; i<16*512; i+=128){
    int r = i>>9, c = i&511;
    size_t row = bn0 + r;
    float v;
    if(c<64)       v = x1[row*64  + c];
    else if(c<128) v = x2[row*64  + (c-64)];
    else if(c<256) v = x3[row*128 + (c-128)];
    else           v = x4[row*256 + (c-256)];
    cat[i] = v;
  }
  __syncthreads();
  const int og = t & 63;
  const int rg = t >> 6;
  const int o0 = og*8;
  float acc[8][8];
  #pragma unroll
  for(int r=0;r<8;r++){
    #pragma unroll
    for(int j=0;j<8;j++) acc[r][j]=0.f;
  }
  float wA[4][8], wB[4][8];
  W5_LOAD(wA, 0)
  for(int c4=0; c4<128; c4+=2){
    W5_LOAD(wB, c4+1)
    W5_COMPUTE(wA, c4)
    if(c4 < 126) W5_LOAD(wA, c4+2)
    W5_COMPUTE(wB, c4+1)
  }
  float lmx[8], lmn[8];
  #pragma unroll
  for(int j=0;j<8;j++){
    float M=-INFINITY, m=INFINITY;
    #pragma unroll
    for(int r=0;r<8;r++){ M=fmaxf(M,acc[r][j]); m=fminf(m,acc[r][j]); }
    lmx[j]=M; lmn[j]=m;
  }
  if(rg==0){
    #pragma unroll
    for(int j=0;j<8;j++){ redm[o0+j]=lmx[j]; redn[o0+j]=lmn[j]; }
  }
  __syncthreads();
  if(rg==1){
    #pragma unroll
    for(int j=0;j<8;j++){
      int o = o0 + j;
      float M = fmaxf(lmx[j], redm[o]);
      float m = fminf(lmn[j], redn[o]);
      atomicMax(&mxe[b*512+o], encf(M));
      atomicMin(&mne[b*512+o], encf(m));
    }
  }
}

__launch_bounds__(256) __global__ void final_k(const unsigned* mxe, const unsigned* mne,
    const float* g5, const float* b5, const float* Wemb, float* out){
  const int b = blockIdx.x, t = threadIdx.x;
  __shared__ float h[512];
  for(int o=t; o<512; o+=256){
    float mx = decf(mxe[b*512+o]);
    float mn = decf(mne[b*512+o]);
    float a  = g5[o] * RSQ;
    float bo = b5[o];
    float hv = lrelu((a >= 0.f ? a*mx : a*mn) + bo);
    h[o] = hv;
    out[b*512+o] = hv;
  }
  __syncthreads();
  const float* wr = Wemb + (size_t)t*512;
  float s = 0.f;
  for(int o=0;o<512;o+=4){
    float4 w4 = *(const float4*)(wr+o);
    s = fmaf(h[o],w4.x, fmaf(h[o+1],w4.y, fmaf(h[o+2],w4.z, fmaf(h[o+3],w4.w, s))));
  }
  out[4096 + b*256 + t] = s;
}

// ---------------- launch ----------------
extern "C" void kernel_launch(void* const* d_in, const int* in_sizes, int n_in,
                              void* d_out, int out_size, void* d_ws, size_t ws_size,
                              hipStream_t stream) {
  if (ws_size < WS_END * sizeof(float)) return;
  const bool big = ws_size >= WS_BIG_END * sizeof(float);   // deterministic per call

  const float* x0   = (const float*)d_in[0];
  const float* W1   = (const float*)d_in[1];
  const float* g1   = (const float*)d_in[2];
  const float* b1   = (const float*)d_in[3];
  const float* W2   = (const float*)d_in[4];
  const float* g2   = (const float*)d_in[5];
  const float* b2   = (const float*)d_in[6];
  const float* W3   = (const float*)d_in[7];
  const float* g3   = (const float*)d_in[8];
  const float* b3   = (const float*)d_in[9];
  const float* W4   = (const float*)d_in[10];
  const float* g4   = (const float*)d_in[11];
  const float* b4   = (const float*)d_in[12];
  const float* W5   = (const float*)d_in[13];
  const float* g5   = (const float*)d_in[14];
  const float* b5   = (const float*)d_in[15];
  const float* Wemb = (const float*)d_in[16];

  float* ws = (float*)d_ws;
  float* xx = ws + OFF_XX;
  float* x1 = ws + OFF_X1;  float* x2 = ws + OFF_X2;
  float* x3 = ws + OFF_X3;  float* x4 = ws + OFF_X4;
  float* q  = ws + OFF_SC;
  float* bs = ws + OFF_SC + (size_t)BN*64;
  int*   id = (int*)(ws + OFF_ID);
  float* W5Tf = ws + OFF_W5T;
  unsigned* mxe = (unsigned*)(ws + OFF_MX);
  unsigned* mne = (unsigned*)(ws + OFF_MN);
  float* WT2 = ws + OFF_WT2;
  float* WT3 = ws + OFF_WT3;
  float* WT4 = ws + OFF_WT4;
  float* distD = ws + OFF_X3;   // fallback dual-batch (L2/L3)
  float* distS = ws + OFF_X4;   // fallback single-batch (L4)
  float* distB = ws + OFF_BIG;  // big path: all 8 batches
  float* out = (float*)d_out;

  prep_k<<<1024,256,0,stream>>>(W5, W2, W3, W4, W5Tf, WT2, WT3, WT4, mxe, mne);

  // layer 1 (3 -> 64)
  sqnorm_k<3><<<BN/256,256,0,stream>>>(x0, xx);
  sel3_k<<<BN*64/256,256,0,stream>>>(x0, xx, id);
  qp3_k<<<BN*8/256,256,0,stream>>>(x0, W1, q, bs);
  gather64_k<64><<<BN*64/256,256,0,stream>>>(q, bs, id, g1, b1, 0, x1);

  // layer 2 (64 -> 64)
  sqnorm_k<64><<<BN/256,256,0,stream>>>(x1, xx);
  { int nb = big ? 8 : 2; float* db = big ? distB : distD;
    for(int r=0;r<8/nb;r++){
      gemm_dist_k<64><<<dim3(16,16,nb),256,0,stream>>>(x1, xx, db, r*nb);
      sel_k<<<(nb*NN)/4,256,0,stream>>>(db, id, r*nb, nb*NN);
    } }
  qp64T_k<64,64><<<BN*8/256,256,0,stream>>>(x1, WT2, 0, q, bs);
  gather64_k<64><<<BN*64/256,256,0,stream>>>(q, bs, id, g2, b2, 0, x2);

  // layer 3 (64 -> 128)
  sqnorm_k<64><<<BN/256,256,0,stream>>>(x2, xx);
  { int nb = big ? 8 : 2; float* db = big ? distB : distD;
    for(int r=0;r<8/nb;r++){
      gemm_dist_k<64><<<dim3(16,16,nb),256,0,stream>>>(x2, xx, db, r*nb);
      sel_k<<<(nb*NN)/4,256,0,stream>>>(db, id, r*nb, nb*NN);
    } }
  for(int cb=0; cb<128; cb+=64){
    qp64T_k<64,128><<<BN*8/256,256,0,stream>>>(x2, WT3, cb, q, bs);
    gather64_k<128><<<BN*64/256,256,0,stream>>>(q, bs, id, g3, b3, cb, x3);
  }

  // layer 4 (128 -> 256)
  sqnorm_k<128><<<BN/256,256,0,stream>>>(x3, xx);
  { int nb = big ? 8 : 1; float* db = big ? distB : distS;
    for(int r=0;r<8/nb;r++){
      gemm_dist_k<128><<<dim3(16,16,nb),256,0,stream>>>(x3, xx, db, r*nb);
      sel_k<<<(nb*NN)/4,256,0,stream>>>(db, id, r*nb, nb*NN);
    } }
  for(int cb=0; cb<256; cb+=64){
    qp64T_k<128,256><<<BN*8/256,256,0,stream>>>(x3, WT4, cb, q, bs);
    gather64_k<256><<<BN*64/256,256,0,stream>>>(q, bs, id, g4, b4, cb, x4);
  }

  // head
  w5max_k<<<BB*(NN/16),128,0,stream>>>(x1, x2, x3, x4, W5Tf, mxe, mne);
  final_k<<<BB,256,0,stream>>>(mxe, mne, g5, b5, Wemb, out);
}